// Round 14
// baseline (503.703 us; speedup 1.0000x reference)
//
#include <hip/hip_runtime.h>
#include <stdint.h>

#define D_ 1024
#define H_ 16
#define HD_ 64
#define FF_ 4096
#define T_ 4096
#define TC_ 4097
#define CHUNK_ 128
#define NCH_ 32
#define NV_ 9
#define LAYERS_ 8

// ws layout (floats) — proven range
#define WS_QKV 0          // [3072]
#define WS_GU 3072        // [8192]
#define WS_HID 11264      // [1024]
#define WS_PART 12288     // [16*32*66 = 33792]

// KV tensor geometry in float4 units
#define HEAD_F4 65536     // 4096*64/4 per head (rows < T)
#define DSTH_F4 65552     // 4097*64/4 dst head stride
#define HALF_F4 524288    // half tensor (8 heads' worth of float4s = 1M/2)

static constexpr float SCALE_ = 0.49497474683058327f; // 1.4/sqrt(8)
static constexpr float EPS_ = 1e-5f;

typedef float nf4 __attribute__((ext_vector_type(4)));   // native vec for NT builtins

__device__ __forceinline__ float wave_sum(float v) {
    #pragma unroll
    for (int off = 32; off; off >>= 1) v += __shfl_down(v, off, 64);
    return v;
}
__device__ __forceinline__ float wave_max(float v) {
    #pragma unroll
    for (int off = 32; off; off >>= 1) v = fmaxf(v, __shfl_down(v, off, 64));
    return v;
}

// copy rows<T of one KV tensor slice: src [16,4096,64] -> dst [16,4097,64]
__device__ __forceinline__ void copy_kv(const float* __restrict__ src, float* __restrict__ dst,
                                        int base4, int rank, int cpb, int t)
{
    long i0 = (long)base4 + (long)rank * cpb;
    for (int j = t; j < cpb; j += 256) {
        long i4 = i0 + j;
        int h = (int)(i4 >> 16);          // / HEAD_F4
        long rem = i4 & (HEAD_F4 - 1);
        nf4 v = __builtin_nontemporal_load((const nf4*)src + i4);
        __builtin_nontemporal_store(v, (nf4*)dst + (long)h * DSTH_F4 + rem);
    }
}

// rms(hid)*lnw -> hn[1024]
__device__ __forceinline__ void rms_to_sm(const float* __restrict__ hid,
                                          const float* __restrict__ lnw,
                                          float* hn, float* wred, int t)
{
    float4 hv = ((const float4*)hid)[t];
    float ssq = hv.x*hv.x + hv.y*hv.y + hv.z*hv.z + hv.w*hv.w;
    ssq = wave_sum(ssq);
    if ((t & 63) == 0) wred[t >> 6] = ssq;
    __syncthreads();
    float rms = rsqrtf((wred[0] + wred[1] + wred[2] + wred[3]) * (1.0f / D_) + EPS_);
    float4 lw = ((const float4*)lnw)[t];
    hn[4*t+0] = hv.x * rms * lw.x;
    hn[4*t+1] = hv.y * rms * lw.y;
    hn[4*t+2] = hv.z * rms * lw.z;
    hn[4*t+3] = hv.w * rms * lw.w;
    __syncthreads();
}

// RT-row x 128-col gemv tile: dst[colbase..+128) += scale * (hsrc[rows] @ W-tile)
template<int RT>
__device__ __forceinline__ void gemv_tile(const float* __restrict__ hsrc,
                                          const float* __restrict__ W, int ncols,
                                          int rowbase, int colbase, float scale,
                                          float* __restrict__ dst, float4* red4, int t)
{
    constexpr int RPG = RT / 8;
    int cg = t & 31, rg = t >> 5;
    int row0 = rowbase + rg * RPG;
    const float* Wp = W + (size_t)row0 * ncols + colbase + cg * 4;
    float4 acc = make_float4(0.f, 0.f, 0.f, 0.f);
    #pragma unroll
    for (int r = 0; r < RPG; ++r) {
        float hs = hsrc[row0 + r];
        float4 w4 = *(const float4*)(Wp + (size_t)r * ncols);
        acc.x += hs*w4.x; acc.y += hs*w4.y; acc.z += hs*w4.z; acc.w += hs*w4.w;
    }
    red4[t] = acc;
    __syncthreads();
    if (t < 32) {
        float4 s = red4[t];
        #pragma unroll
        for (int g = 1; g < 8; ++g) {
            float4 r4 = red4[t + 32*g];
            s.x += r4.x; s.y += r4.y; s.z += r4.z; s.w += r4.w;
        }
        float* d = dst + colbase + t*4;
        atomicAdd(d+0, scale*s.x);
        atomicAdd(d+1, scale*s.y);
        atomicAdd(d+2, scale*s.z);
        atomicAdd(d+3, scale*s.w);
    }
    __syncthreads();
}

__global__ void k_init(const float* __restrict__ embed, float* __restrict__ hid,
                       float* __restrict__ accQKV) {
    int t = threadIdx.x;
    ((float4*)hid)[t] = ((const float4*)embed)[t];
    for (int i = t; i < 3072; i += 256) accQKV[i] = 0.f;
}

// grid (NCOLS/128, 1024/RT, NZ+1): z<NZ compute, z==NZ -> copy plane
template<int NCOLS, int RT, int NZ, int CPB>
__global__ void k_rms_gemv(const float* __restrict__ hidden, const float* __restrict__ lnw,
                           const float* __restrict__ W0, const float* __restrict__ W1,
                           const float* __restrict__ W2, float* __restrict__ out,
                           const float* __restrict__ csrc, float* __restrict__ cdst, int cbase4)
{
    int t = threadIdx.x;
    if (blockIdx.z == NZ) {
        copy_kv(csrc, cdst, cbase4, blockIdx.y * gridDim.x + blockIdx.x, CPB, t);
        return;
    }
    __shared__ float hn[D_];
    __shared__ float wred[4];
    __shared__ float4 red4s[256];
    rms_to_sm(hidden, lnw, hn, wred, t);
    const float* W = (blockIdx.z == 0) ? W0 : (blockIdx.z == 1 ? W1 : W2);
    gemv_tile<RT>(hn, W, NCOLS, blockIdx.y*RT, blockIdx.x*128, 1.f,
                  out + (size_t)blockIdx.z * NCOLS, red4s, t);
}

// flash-decode chunk: grid (NCH_=32, H_); block 256. Exactly 2 blocks/CU.
// Bulk KV copy-out removed (ridden in other nodes); only row T written here.
__global__ void k_attn_f(const float* __restrict__ kcache, const float* __restrict__ vcache,
                         const float* __restrict__ qkv, const int* __restrict__ posp,
                         float* __restrict__ kc_out, float* __restrict__ vc_out,
                         float* __restrict__ part)
{
    int c = blockIdx.x, h = blockIdx.y, t = threadIdx.x;
    __shared__ float qr[64], kr[64], sc[132], wr2[8];
    __shared__ float4 red4[256];
    if (t < 32) {
        float pos = (float)(*posp);
        float inv = expf(-(float)t * (9.210340371976184f / 32.0f)); // 10000^(-t/32)
        float ang = pos * inv;
        float cs = cosf(ang), sn = sinf(ang);
        float q1 = qkv[h*64 + t], q2 = qkv[h*64 + t + 32];
        qr[t] = q1*cs - q2*sn; qr[t+32] = q1*sn + q2*cs;
        float k1 = qkv[1024 + h*64 + t], k2 = qkv[1024 + h*64 + t + 32];
        kr[t] = k1*cs - k2*sn; kr[t+32] = k1*sn + k2*cs;
    }

    int kstart = c * CHUNK_;
    int nk = (c == NCH_-1) ? (TC_ - kstart) : CHUNK_;   // 128, last: 129
    int d4 = (t & 15) * 4;      // column group (16 x 4 dims)
    int kl0 = t >> 4;           // key lane base; keys kl0 + 16j

    // ---- prefetch V into registers; write row T of vc_out (new v) ----
    nf4 vreg[NV_];
    #pragma unroll
    for (int j = 0; j < NV_; ++j) {
        int kl = kl0 + 16 * j;
        if (kl < nk) {
            int key = kstart + kl;
            if (key < T_) {
                vreg[j] = __builtin_nontemporal_load((const nf4*)(vcache + ((size_t)h*T_ + key)*HD_ + d4));
            } else {
                vreg[j] = *(const nf4*)(qkv + 2048 + h*64 + d4);
                __builtin_nontemporal_store(vreg[j], (nf4*)(vc_out + ((size_t)h*TC_ + key)*HD_ + d4));
            }
        }
    }

    __syncthreads();   // qr/kr ready
    // ---- pass A: scores (16 lanes/key, float4); write row T of kc_out (roped k) ----
    nf4 qv = *(const nf4*)&qr[d4];
    #pragma unroll
    for (int j = 0; j < NV_; ++j) {
        int kl = kl0 + 16 * j;
        if (kl < nk) {
            int key = kstart + kl;
            nf4 kv;
            if (key < T_) {
                kv = __builtin_nontemporal_load((const nf4*)(kcache + ((size_t)h*T_ + key)*HD_ + d4));
            } else {
                kv = *(const nf4*)&kr[d4];
                __builtin_nontemporal_store(kv, (nf4*)(kc_out + ((size_t)h*TC_ + key)*HD_ + d4));
            }
            float pd = qv.x*kv.x + qv.y*kv.y + qv.z*kv.z + qv.w*kv.w;
            pd += __shfl_down(pd, 8, 16);
            pd += __shfl_down(pd, 4, 16);
            pd += __shfl_down(pd, 2, 16);
            pd += __shfl_down(pd, 1, 16);
            if ((t & 15) == 0) sc[kl] = pd * 0.125f;
        }
    }
    __syncthreads();
    // ---- parallel chunk softmax (nk <= 129 <= 256) ----
    float m = (t < nk) ? sc[t] : -INFINITY;
    m = wave_max(m);
    if ((t & 63) == 0) wr2[t >> 6] = m;
    __syncthreads();
    m = fmaxf(fmaxf(wr2[0], wr2[1]), fmaxf(wr2[2], wr2[3]));
    float e = 0.f;
    if (t < nk) { e = __expf(sc[t] - m); sc[t] = e; }
    float s = wave_sum(e);
    if ((t & 63) == 0) wr2[4 + (t >> 6)] = s;
    __syncthreads();
    float* pb = part + ((size_t)h*NCH_ + c)*66;
    if (t == 0) { pb[0] = m; pb[1] = wr2[4]+wr2[5]+wr2[6]+wr2[7]; }
    __syncthreads();
    // ---- pass B: weighted V from registers ----
    float4 acc = make_float4(0.f, 0.f, 0.f, 0.f);
    #pragma unroll
    for (int j = 0; j < NV_; ++j) {
        int kl = kl0 + 16 * j;
        if (kl < nk) {
            float w = sc[kl];
            acc.x += w*vreg[j].x; acc.y += w*vreg[j].y;
            acc.z += w*vreg[j].z; acc.w += w*vreg[j].w;
        }
    }
    red4[t] = acc;
    __syncthreads();
    if (t < 16) {
        float4 s4 = red4[t];
        #pragma unroll
        for (int g = 1; g < 16; ++g) {
            float4 r4 = red4[t + 16*g];
            s4.x += r4.x; s4.y += r4.y; s4.z += r4.z; s4.w += r4.w;
        }
        pb[2 + t*4 + 0] = s4.x;
        pb[2 + t*4 + 1] = s4.y;
        pb[2 + t*4 + 2] = s4.z;
        pb[2 + t*4 + 3] = s4.w;
    }
}

// combine (per-head) + gemv 64 rows of Wo; hidden += SCALE*partial.
// grid (8, 32): y<16 compute (y=head), y>=16 copy. Block (0,0) zeroes accGU.
__global__ void k_wo(const float* __restrict__ part, const float* __restrict__ Wo,
                     float* __restrict__ hidden, float* __restrict__ accGU,
                     const float* __restrict__ csrc, float* __restrict__ cdst, int cbase4)
{
    int t = threadIdx.x;
    if (blockIdx.y >= 16) {
        copy_kv(csrc, cdst, cbase4, (blockIdx.y - 16) * 8 + blockIdx.x, 4096, t);
        return;
    }
    int h = blockIdx.y;
    if (blockIdx.x == 0 && blockIdx.y == 0)
        for (int i = t; i < 2*FF_; i += 256) accGU[i] = 0.f;
    __shared__ float oh[64];
    __shared__ float4 red4s[256];
    if (t < 64) {
        const float* pb = part + (size_t)h * NCH_ * 66;
        float M = -INFINITY;
        for (int c = 0; c < NCH_; ++c) M = fmaxf(M, pb[c*66]);
        float S = 0.f, O = 0.f;
        for (int c = 0; c < NCH_; ++c) {
            float e = __expf(pb[c*66] - M);
            S += pb[c*66 + 1] * e;
            O += pb[c*66 + 2 + t] * e;
        }
        oh[t] = O / S;
    }
    __syncthreads();
    gemv_tile<64>(oh - h*64, Wo, D_, h*64, blockIdx.x*128, SCALE_, hidden, red4s, t);
}

// hidden += SCALE * (silu(g)*u) @ Wd ; grid (8, 48): y<32 compute, y>=32 copy.
// Block (0,0) zeroes accQKV.
__global__ void k_down(const float* __restrict__ gu, const float* __restrict__ Wd,
                       float* __restrict__ hidden, float* __restrict__ accQKV,
                       const float* __restrict__ csrc, float* __restrict__ cdst, int cbase4)
{
    int t = threadIdx.x;
    if (blockIdx.y >= 32) {
        copy_kv(csrc, cdst, cbase4, (blockIdx.y - 32) * 8 + blockIdx.x, 4096, t);
        return;
    }
    if (blockIdx.x == 0 && blockIdx.y == 0)
        for (int i = t; i < 3072; i += 256) accQKV[i] = 0.f;
    __shared__ float act[128];
    __shared__ float4 red4s[256];
    int rowbase = blockIdx.y * 128;
    if (t < 128) {
        float g = gu[rowbase + t];
        float u = gu[FF_ + rowbase + t];
        act[t] = g / (1.f + __expf(-g)) * u;
    }
    __syncthreads();
    gemv_tile<128>(act - rowbase, Wd, D_, rowbase, blockIdx.x*128, SCALE_, hidden, red4s, t);
}

__global__ void k_final(const float* __restrict__ hidden, const float* __restrict__ nw,
                        float* __restrict__ out)
{
    int t = threadIdx.x;
    __shared__ float wred[4];
    float4 hv = ((const float4*)hidden)[t];
    float ssq = hv.x*hv.x + hv.y*hv.y + hv.z*hv.z + hv.w*hv.w;
    ssq = wave_sum(ssq);
    if ((t & 63) == 0) wred[t >> 6] = ssq;
    __syncthreads();
    float rms = rsqrtf((wred[0] + wred[1] + wred[2] + wred[3]) * (1.0f / D_) + EPS_);
    float4 w = ((const float4*)nw)[t];
    float4 ob;
    ob.x = hv.x * rms * w.x; ob.y = hv.y * rms * w.y;
    ob.z = hv.z * rms * w.z; ob.w = hv.w * rms * w.w;
    ((float4*)out)[t] = ob;
}

// role indices: 0 embed, 1+2i k_i, 2+2i v_i, 17 ln1, 18 ln2, 19 norm,
//               20 Wq, 21 Wk, 22 Wv, 23 Wo, 24 Wg, 25 Wu, 26 Wd, 27 pos
static const int ROLE_SIZES[28] = {
    1024,
    4194304,4194304,4194304,4194304,4194304,4194304,4194304,4194304,
    4194304,4194304,4194304,4194304,4194304,4194304,4194304,4194304,
    8192, 8192, 1024,
    8388608, 8388608, 8388608, 8388608,
    33554432, 33554432, 33554432,
    1
};

extern "C" void kernel_launch(void* const* d_in, const int* in_sizes, int n_in,
                              void* d_out, int out_size, void* d_ws, size_t ws_size,
                              hipStream_t stream)
{
    int perm[28];
    bool matched = false;
    auto try_perm = [&](const int* cand) {
        if (matched) return;
        for (int r = 0; r < 28; ++r)
            if (in_sizes[cand[r]] != ROLE_SIZES[r]) return;
        for (int r = 0; r < 28; ++r) perm[r] = cand[r];
        matched = true;
    };
    {   int c[28]; for (int r = 0; r < 28; ++r) c[r] = r; try_perm(c); }  // C0 dict (matched)
    {   int c[28];
        c[0]=0; c[27]=1;
        for (int i = 0; i < 8; ++i) { c[1+2*i]=2+2*i; c[2+2*i]=3+2*i; }
        c[17]=18; c[18]=19; c[19]=20;
        c[20]=21; c[21]=22; c[22]=23; c[23]=24; c[24]=25; c[25]=26; c[26]=27;
        try_perm(c); }                                                    // C1 signature
    if (!matched) { for (int r = 0; r < 28; ++r) perm[r] = r; }

    const float* embed = (const float*)d_in[perm[0]];
    const float* kcs[LAYERS_];
    const float* vcs[LAYERS_];
    for (int i = 0; i < LAYERS_; ++i) {
        kcs[i] = (const float*)d_in[perm[1+2*i]];
        vcs[i] = (const float*)d_in[perm[2+2*i]];
    }
    const float* ln1 = (const float*)d_in[perm[17]];
    const float* ln2 = (const float*)d_in[perm[18]];
    const float* nw  = (const float*)d_in[perm[19]];
    const float* Wq  = (const float*)d_in[perm[20]];
    const float* Wk  = (const float*)d_in[perm[21]];
    const float* Wv  = (const float*)d_in[perm[22]];
    const float* Wo  = (const float*)d_in[perm[23]];
    const float* Wg  = (const float*)d_in[perm[24]];
    const float* Wu  = (const float*)d_in[perm[25]];
    const float* Wd  = (const float*)d_in[perm[26]];
    const int*   pos = (const int*)d_in[perm[27]];

    float* out = (float*)d_out;
    float* ws = (float*)d_ws;
    float* accQKV = ws + WS_QKV;
    float* accGU  = ws + WS_GU;
    float* hid    = ws + WS_HID;
    float* part   = ws + WS_PART;

    (void)out_size; (void)ws_size; (void)n_in;

    k_init<<<1, 256, 0, stream>>>(embed, hid, accQKV);

    const size_t KVSZ = (size_t)H_ * TC_ * HD_; // 4,195,328
    for (int i = 0; i < LAYERS_; ++i) {
        float* kco = out + 1024 + (size_t)i * 2 * KVSZ;
        float* vco = kco + KVSZ;

        // QKV gemv (384 compute) + K copy first half (128) = 512 blocks
        k_rms_gemv<D_, 64, 3, 4096><<<dim3(8, 16, 4), 256, 0, stream>>>(
            hid, ln1 + i*D_,
            Wq + (size_t)i*D_*D_, Wk + (size_t)i*D_*D_, Wv + (size_t)i*D_*D_,
            accQKV, kcs[i], kco, 0);

        k_attn_f<<<dim3(NCH_, H_), 256, 0, stream>>>(kcs[i], vcs[i], accQKV, pos,
                                                     kco, vco, part);

        // wo (128 compute) + K copy second half (128) = 256 blocks
        k_wo<<<dim3(8, 32), 256, 0, stream>>>(part, Wo + (size_t)i*D_*D_, hid, accGU,
                                              kcs[i], kco, HALF_F4);

        // G/U gemv (512 compute) + V copy first half (256 x 2048) = 768 blocks
        k_rms_gemv<FF_, 128, 2, 2048><<<dim3(32, 8, 3), 256, 0, stream>>>(
            hid, ln2 + i*D_,
            Wg + (size_t)i*D_*FF_, Wu + (size_t)i*D_*FF_, nullptr,
            accGU, vcs[i], vco, 0);

        // down (256 compute) + V copy second half (128) = 384 blocks
        k_down<<<dim3(8, 48), 256, 0, stream>>>(accGU, Wd + (size_t)i*FF_*D_, hid, accQKV,
                                                vcs[i], vco, HALF_F4);
    }
    k_final<<<1, 256, 0, stream>>>(hid, nw, out);
}

// Round 15
// 371.785 us; speedup vs baseline: 1.3548x; 1.3548x over previous
//
#include <hip/hip_runtime.h>
#include <stdint.h>

#define D_ 1024
#define H_ 16
#define HD_ 64
#define FF_ 4096
#define T_ 4096
#define TC_ 4097
#define CHUNK_ 128
#define NCH_ 32
#define NV_ 9
#define LAYERS_ 8

// ws layout (floats) — proven range
#define WS_QKV 0          // [3072]
#define WS_GU 3072        // [8192]
#define WS_HID 11264      // [1024]
#define WS_PART 12288     // [16*32*66 = 33792]

static constexpr float SCALE_ = 0.49497474683058327f; // 1.4/sqrt(8)
static constexpr float EPS_ = 1e-5f;

typedef float nf4 __attribute__((ext_vector_type(4)));   // native vec for NT builtins

__device__ __forceinline__ float wave_sum(float v) {
    #pragma unroll
    for (int off = 32; off; off >>= 1) v += __shfl_down(v, off, 64);
    return v;
}
__device__ __forceinline__ float wave_max(float v) {
    #pragma unroll
    for (int off = 32; off; off >>= 1) v = fmaxf(v, __shfl_down(v, off, 64));
    return v;
}

// rms(hid)*lnw -> hn[1024]
__device__ __forceinline__ void rms_to_sm(const float* __restrict__ hid,
                                          const float* __restrict__ lnw,
                                          float* hn, float* wred, int t)
{
    float4 hv = ((const float4*)hid)[t];
    float ssq = hv.x*hv.x + hv.y*hv.y + hv.z*hv.z + hv.w*hv.w;
    ssq = wave_sum(ssq);
    if ((t & 63) == 0) wred[t >> 6] = ssq;
    __syncthreads();
    float rms = rsqrtf((wred[0] + wred[1] + wred[2] + wred[3]) * (1.0f / D_) + EPS_);
    float4 lw = ((const float4*)lnw)[t];
    hn[4*t+0] = hv.x * rms * lw.x;
    hn[4*t+1] = hv.y * rms * lw.y;
    hn[4*t+2] = hv.z * rms * lw.z;
    hn[4*t+3] = hv.w * rms * lw.w;
    __syncthreads();
}

// RT-row x 128-col gemv tile: dst[colbase..+128) += scale * (hsrc[rows] @ W-tile)
// 32 col-groups (x4 floats) x 8 row-groups (RT/8 rows each); RT/8 loads in flight/thread.
template<int RT>
__device__ __forceinline__ void gemv_tile(const float* __restrict__ hsrc,
                                          const float* __restrict__ W, int ncols,
                                          int rowbase, int colbase, float scale,
                                          float* __restrict__ dst, float4* red4, int t)
{
    constexpr int RPG = RT / 8;
    int cg = t & 31, rg = t >> 5;
    int row0 = rowbase + rg * RPG;
    const float* Wp = W + (size_t)row0 * ncols + colbase + cg * 4;
    float4 acc = make_float4(0.f, 0.f, 0.f, 0.f);
    #pragma unroll
    for (int r = 0; r < RPG; ++r) {
        float hs = hsrc[row0 + r];
        float4 w4 = *(const float4*)(Wp + (size_t)r * ncols);
        acc.x += hs*w4.x; acc.y += hs*w4.y; acc.z += hs*w4.z; acc.w += hs*w4.w;
    }
    red4[t] = acc;
    __syncthreads();
    if (t < 32) {
        float4 s = red4[t];
        #pragma unroll
        for (int g = 1; g < 8; ++g) {
            float4 r4 = red4[t + 32*g];
            s.x += r4.x; s.y += r4.y; s.z += r4.z; s.w += r4.w;
        }
        float* d = dst + colbase + t*4;
        atomicAdd(d+0, scale*s.x);
        atomicAdd(d+1, scale*s.y);
        atomicAdd(d+2, scale*s.z);
        atomicAdd(d+3, scale*s.w);
    }
    __syncthreads();
}

__global__ void k_init(const float* __restrict__ embed, float* __restrict__ hid,
                       float* __restrict__ accQKV) {
    int t = threadIdx.x;
    ((float4*)hid)[t] = ((const float4*)embed)[t];
    for (int i = t; i < 3072; i += 256) accQKV[i] = 0.f;
}

// grid (NCOLS/128, 1024/RT, nmat)
template<int NCOLS, int RT>
__global__ void k_rms_gemv(const float* __restrict__ hidden, const float* __restrict__ lnw,
                           const float* __restrict__ W0, const float* __restrict__ W1,
                           const float* __restrict__ W2, float* __restrict__ out)
{
    int t = threadIdx.x;
    __shared__ float hn[D_];
    __shared__ float wred[4];
    __shared__ float4 red4s[256];
    rms_to_sm(hidden, lnw, hn, wred, t);
    const float* W = (blockIdx.z == 0) ? W0 : (blockIdx.z == 1 ? W1 : W2);
    gemv_tile<RT>(hn, W, NCOLS, blockIdx.y*RT, blockIdx.x*128, 1.f,
                  out + (size_t)blockIdx.z * NCOLS, red4s, t);
}

// flash-decode chunk: grid (NCH_=32, H_); block 256. Exactly 2 blocks/CU.
// Chunks 0..30: 128 keys; chunk 31: 129 keys (incl. new key at row T).
// V prefetched to regs before softmax; NT loads/stores for stream-once KV + copy-out.
__global__ void k_attn_f(const float* __restrict__ kcache, const float* __restrict__ vcache,
                         const float* __restrict__ qkv, const int* __restrict__ posp,
                         float* __restrict__ kc_out, float* __restrict__ vc_out,
                         float* __restrict__ part)
{
    int c = blockIdx.x, h = blockIdx.y, t = threadIdx.x;
    __shared__ float qr[64], kr[64], sc[132], wr2[8];
    __shared__ float4 red4[256];
    if (t < 32) {
        float pos = (float)(*posp);
        float inv = expf(-(float)t * (9.210340371976184f / 32.0f)); // 10000^(-t/32)
        float ang = pos * inv;
        float cs = cosf(ang), sn = sinf(ang);
        float q1 = qkv[h*64 + t], q2 = qkv[h*64 + t + 32];
        qr[t] = q1*cs - q2*sn; qr[t+32] = q1*sn + q2*cs;
        float k1 = qkv[1024 + h*64 + t], k2 = qkv[1024 + h*64 + t + 32];
        kr[t] = k1*cs - k2*sn; kr[t+32] = k1*sn + k2*cs;
    }

    int kstart = c * CHUNK_;
    int nk = (c == NCH_-1) ? (TC_ - kstart) : CHUNK_;   // 128, last: 129
    int d4 = (t & 15) * 4;      // column group (16 x 4 dims)
    int kl0 = t >> 4;           // key lane base; keys kl0 + 16j

    // ---- prefetch V into registers (issued before K-dot + softmax) ----
    nf4 vreg[NV_];
    #pragma unroll
    for (int j = 0; j < NV_; ++j) {
        int kl = kl0 + 16 * j;
        if (kl < nk) {
            int key = kstart + kl;
            if (key < T_)
                vreg[j] = __builtin_nontemporal_load((const nf4*)(vcache + ((size_t)h*T_ + key)*HD_ + d4));
            else
                vreg[j] = *(const nf4*)(qkv + 2048 + h*64 + d4);
        }
    }

    __syncthreads();   // qr/kr ready
    // ---- pass A: scores (16 lanes/key, float4) + NT K copy ----
    nf4 qv = *(const nf4*)&qr[d4];
    #pragma unroll
    for (int j = 0; j < NV_; ++j) {
        int kl = kl0 + 16 * j;
        if (kl < nk) {
            int key = kstart + kl;
            nf4 kv;
            if (key < T_) kv = __builtin_nontemporal_load((const nf4*)(kcache + ((size_t)h*T_ + key)*HD_ + d4));
            else          kv = *(const nf4*)&kr[d4];
            float pd = qv.x*kv.x + qv.y*kv.y + qv.z*kv.z + qv.w*kv.w;
            pd += __shfl_down(pd, 8, 16);
            pd += __shfl_down(pd, 4, 16);
            pd += __shfl_down(pd, 2, 16);
            pd += __shfl_down(pd, 1, 16);
            if ((t & 15) == 0) sc[kl] = pd * 0.125f;
            __builtin_nontemporal_store(kv, (nf4*)(kc_out + ((size_t)h*TC_ + key)*HD_ + d4));
        }
    }
    // ---- NT V copy (from regs, overlaps softmax issue) ----
    #pragma unroll
    for (int j = 0; j < NV_; ++j) {
        int kl = kl0 + 16 * j;
        if (kl < nk) {
            int key = kstart + kl;
            __builtin_nontemporal_store(vreg[j], (nf4*)(vc_out + ((size_t)h*TC_ + key)*HD_ + d4));
        }
    }
    __syncthreads();
    // ---- parallel chunk softmax (nk <= 129 <= 256) ----
    float m = (t < nk) ? sc[t] : -INFINITY;
    m = wave_max(m);
    if ((t & 63) == 0) wr2[t >> 6] = m;
    __syncthreads();
    m = fmaxf(fmaxf(wr2[0], wr2[1]), fmaxf(wr2[2], wr2[3]));
    float e = 0.f;
    if (t < nk) { e = __expf(sc[t] - m); sc[t] = e; }
    float s = wave_sum(e);
    if ((t & 63) == 0) wr2[4 + (t >> 6)] = s;
    __syncthreads();
    float* pb = part + ((size_t)h*NCH_ + c)*66;
    if (t == 0) { pb[0] = m; pb[1] = wr2[4]+wr2[5]+wr2[6]+wr2[7]; }
    __syncthreads();
    // ---- pass B: weighted V from registers ----
    float4 acc = make_float4(0.f, 0.f, 0.f, 0.f);
    #pragma unroll
    for (int j = 0; j < NV_; ++j) {
        int kl = kl0 + 16 * j;
        if (kl < nk) {
            float w = sc[kl];
            acc.x += w*vreg[j].x; acc.y += w*vreg[j].y;
            acc.z += w*vreg[j].z; acc.w += w*vreg[j].w;
        }
    }
    red4[t] = acc;
    __syncthreads();
    if (t < 16) {
        float4 s4 = red4[t];
        #pragma unroll
        for (int g = 1; g < 16; ++g) {
            float4 r4 = red4[t + 16*g];
            s4.x += r4.x; s4.y += r4.y; s4.z += r4.z; s4.w += r4.w;
        }
        pb[2 + t*4 + 0] = s4.x;
        pb[2 + t*4 + 1] = s4.y;
        pb[2 + t*4 + 2] = s4.z;
        pb[2 + t*4 + 3] = s4.w;
    }
}

// combine (per-head) + gemv 64 rows of Wo; hidden += SCALE*partial. grid (8, 16).
// Block (0,0) zeroes accGU.
__global__ void k_wo(const float* __restrict__ part, const float* __restrict__ Wo,
                     float* __restrict__ hidden, float* __restrict__ accGU)
{
    int h = blockIdx.y, t = threadIdx.x;
    if (blockIdx.x == 0 && blockIdx.y == 0)
        for (int i = t; i < 2*FF_; i += 256) accGU[i] = 0.f;
    __shared__ float oh[64];
    __shared__ float4 red4s[256];
    if (t < 64) {
        const float* pb = part + (size_t)h * NCH_ * 66;
        float M = -INFINITY;
        for (int c = 0; c < NCH_; ++c) M = fmaxf(M, pb[c*66]);
        float S = 0.f, O = 0.f;
        for (int c = 0; c < NCH_; ++c) {
            float e = __expf(pb[c*66] - M);
            S += pb[c*66 + 1] * e;
            O += pb[c*66 + 2 + t] * e;
        }
        oh[t] = O / S;
    }
    __syncthreads();
    gemv_tile<64>(oh - h*64, Wo, D_, h*64, blockIdx.x*128, SCALE_, hidden, red4s, t);
}

// hidden += SCALE * (silu(g)*u) @ Wd ; grid (8, 32): x = coltile(128), y = rowtile(128 of 4096).
// Block (0,0) zeroes accQKV.
__global__ void k_down(const float* __restrict__ gu, const float* __restrict__ Wd,
                       float* __restrict__ hidden, float* __restrict__ accQKV)
{
    int t = threadIdx.x;
    if (blockIdx.x == 0 && blockIdx.y == 0)
        for (int i = t; i < 3072; i += 256) accQKV[i] = 0.f;
    __shared__ float act[128];
    __shared__ float4 red4s[256];
    int rowbase = blockIdx.y * 128;
    if (t < 128) {
        float g = gu[rowbase + t];
        float u = gu[FF_ + rowbase + t];
        act[t] = g / (1.f + __expf(-g)) * u;
    }
    __syncthreads();
    gemv_tile<128>(act - rowbase, Wd, D_, rowbase, blockIdx.x*128, SCALE_, hidden, red4s, t);
}

__global__ void k_final(const float* __restrict__ hidden, const float* __restrict__ nw,
                        float* __restrict__ out)
{
    int t = threadIdx.x;
    __shared__ float wred[4];
    float4 hv = ((const float4*)hidden)[t];
    float ssq = hv.x*hv.x + hv.y*hv.y + hv.z*hv.z + hv.w*hv.w;
    ssq = wave_sum(ssq);
    if ((t & 63) == 0) wred[t >> 6] = ssq;
    __syncthreads();
    float rms = rsqrtf((wred[0] + wred[1] + wred[2] + wred[3]) * (1.0f / D_) + EPS_);
    float4 w = ((const float4*)nw)[t];
    float4 ob;
    ob.x = hv.x * rms * w.x; ob.y = hv.y * rms * w.y;
    ob.z = hv.z * rms * w.z; ob.w = hv.w * rms * w.w;
    ((float4*)out)[t] = ob;
}

// role indices: 0 embed, 1+2i k_i, 2+2i v_i, 17 ln1, 18 ln2, 19 norm,
//               20 Wq, 21 Wk, 22 Wv, 23 Wo, 24 Wg, 25 Wu, 26 Wd, 27 pos
static const int ROLE_SIZES[28] = {
    1024,
    4194304,4194304,4194304,4194304,4194304,4194304,4194304,4194304,
    4194304,4194304,4194304,4194304,4194304,4194304,4194304,4194304,
    8192, 8192, 1024,
    8388608, 8388608, 8388608, 8388608,
    33554432, 33554432, 33554432,
    1
};

extern "C" void kernel_launch(void* const* d_in, const int* in_sizes, int n_in,
                              void* d_out, int out_size, void* d_ws, size_t ws_size,
                              hipStream_t stream)
{
    int perm[28];
    bool matched = false;
    auto try_perm = [&](const int* cand) {
        if (matched) return;
        for (int r = 0; r < 28; ++r)
            if (in_sizes[cand[r]] != ROLE_SIZES[r]) return;
        for (int r = 0; r < 28; ++r) perm[r] = cand[r];
        matched = true;
    };
    {   int c[28]; for (int r = 0; r < 28; ++r) c[r] = r; try_perm(c); }  // C0 dict (matched)
    {   int c[28];
        c[0]=0; c[27]=1;
        for (int i = 0; i < 8; ++i) { c[1+2*i]=2+2*i; c[2+2*i]=3+2*i; }
        c[17]=18; c[18]=19; c[19]=20;
        c[20]=21; c[21]=22; c[22]=23; c[23]=24; c[24]=25; c[25]=26; c[26]=27;
        try_perm(c); }                                                    // C1 signature
    if (!matched) { for (int r = 0; r < 28; ++r) perm[r] = r; }

    const float* embed = (const float*)d_in[perm[0]];
    const float* kcs[LAYERS_];
    const float* vcs[LAYERS_];
    for (int i = 0; i < LAYERS_; ++i) {
        kcs[i] = (const float*)d_in[perm[1+2*i]];
        vcs[i] = (const float*)d_in[perm[2+2*i]];
    }
    const float* ln1 = (const float*)d_in[perm[17]];
    const float* ln2 = (const float*)d_in[perm[18]];
    const float* nw  = (const float*)d_in[perm[19]];
    const float* Wq  = (const float*)d_in[perm[20]];
    const float* Wk  = (const float*)d_in[perm[21]];
    const float* Wv  = (const float*)d_in[perm[22]];
    const float* Wo  = (const float*)d_in[perm[23]];
    const float* Wg  = (const float*)d_in[perm[24]];
    const float* Wu  = (const float*)d_in[perm[25]];
    const float* Wd  = (const float*)d_in[perm[26]];
    const int*   pos = (const int*)d_in[perm[27]];

    float* out = (float*)d_out;
    float* ws = (float*)d_ws;
    float* accQKV = ws + WS_QKV;
    float* accGU  = ws + WS_GU;
    float* hid    = ws + WS_HID;
    float* part   = ws + WS_PART;

    (void)out_size; (void)ws_size; (void)n_in;

    k_init<<<1, 256, 0, stream>>>(embed, hid, accQKV);

    const size_t KVSZ = (size_t)H_ * TC_ * HD_; // 4,195,328
    for (int i = 0; i < LAYERS_; ++i) {
        float* kco = out + 1024 + (size_t)i * 2 * KVSZ;
        float* vco = kco + KVSZ;

        k_rms_gemv<D_, 64><<<dim3(8, 16, 3), 256, 0, stream>>>(
            hid, ln1 + i*D_,
            Wq + (size_t)i*D_*D_, Wk + (size_t)i*D_*D_, Wv + (size_t)i*D_*D_,
            accQKV);

        k_attn_f<<<dim3(NCH_, H_), 256, 0, stream>>>(kcs[i], vcs[i], accQKV, pos,
                                                     kco, vco, part);

        k_wo<<<dim3(8, 16), 256, 0, stream>>>(part, Wo + (size_t)i*D_*D_, hid, accGU);

        k_rms_gemv<FF_, 128><<<dim3(32, 8, 2), 256, 0, stream>>>(
            hid, ln2 + i*D_,
            Wg + (size_t)i*D_*FF_, Wu + (size_t)i*D_*FF_, nullptr,
            accGU);

        k_down<<<dim3(8, 32), 256, 0, stream>>>(accGU, Wd + (size_t)i*FF_*D_, hid, accQKV);
    }
    k_final<<<1, 256, 0, stream>>>(hid, nw, out);
}